// Round 7
// baseline (82.288 us; speedup 1.0000x reference)
//
#include <hip/hip_runtime.h>

#define NN 512
#define FMAGIC 0x5AD0F1A6u

// ---------------- Kernel 1: S = P * P^T (verbatim round-0; bitwise-proven) ----
// 256 blocks x 256 thr, one 32x32 tile per block. Per-block global traffic is
// 128 KB (16x LDS reuse) vs 1 MB for the fused per-anchor dot -> 8x less
// per-CU L1 traffic, which rounds 4/5/6 showed is the binding resource.
__global__ __launch_bounds__(256) void sap_gemm(const float* __restrict__ P,
                                                float* __restrict__ S) {
    __shared__ float As[32][33];
    __shared__ float Bs[32][33];
    const int t  = threadIdx.x;
    const int tx = t & 15, ty = t >> 4;
    const int i0 = blockIdx.y * 32, j0 = blockIdx.x * 32;

    float acc00 = 0.f, acc01 = 0.f, acc10 = 0.f, acc11 = 0.f;

    const int lr = t >> 3;        // 0..31 (tile row for staging)
    const int lc = (t & 7) * 4;   // 0,4,...,28 (tile col for staging, float4)

    for (int kt = 0; kt < NN; kt += 32) {
        float4 a = *(const float4*)&P[(i0 + lr) * NN + kt + lc];
        float4 b = *(const float4*)&P[(j0 + lr) * NN + kt + lc];
        As[lr][lc + 0] = a.x; As[lr][lc + 1] = a.y;
        As[lr][lc + 2] = a.z; As[lr][lc + 3] = a.w;
        Bs[lr][lc + 0] = b.x; Bs[lr][lc + 1] = b.y;
        Bs[lr][lc + 2] = b.z; Bs[lr][lc + 3] = b.w;
        __syncthreads();
#pragma unroll
        for (int kk = 0; kk < 32; kk++) {
            float a0 = As[2 * ty][kk],     a1 = As[2 * ty + 1][kk];
            float b0 = Bs[2 * tx][kk],     b1 = Bs[2 * tx + 1][kk];
            acc00 += a0 * b0; acc01 += a0 * b1;
            acc10 += a1 * b0; acc11 += a1 * b1;
        }
        __syncthreads();
    }
    const int i = i0 + 2 * ty, j = j0 + 2 * tx;
    S[i * NN + j]           = acc00;
    S[i * NN + j + 1]       = acc01;
    S[(i + 1) * NN + j]     = acc10;
    S[(i + 1) * NN + j + 1] = acc11;
}

// ---------------- Kernel 2: rows (verbatim round-0 body) + atomic tail -------
// 256 blocks x 256 thr, anchors i = 2b, 2b+1. Per-block global traffic: 4 KB
// of S + labels. Tail: round-4 proven relaxed agent-scope atomic publish +
// block-0 poll/reduce (no acquire/release L2 storm -- round-3 lesson).
__global__ __launch_bounds__(256) void sap_rows2(const float* __restrict__ S,
                                                 const int* __restrict__ labels,
                                                 unsigned* __restrict__ pa_bits,
                                                 unsigned* __restrict__ flags,
                                                 float* __restrict__ out) {
    __shared__ float srow[NN];
    __shared__ float posf[NN];
    __shared__ int   poslist[NN];
    __shared__ int   npos_cnt;
    __shared__ float wave_part[4];
    __shared__ float pa_out[2];
    __shared__ float sh[256];

    const int t = threadIdx.x;
    const int b = blockIdx.x;
    const int i0 = 2 * b;
    const int wave = t >> 6, lane = t & 63;
    // sigmoid(clip(x/T,-50,50)) = 1/(1+exp2(clip(-x*100*log2e, +-50*log2e)))
    const float C1   = 100.0f * 1.44269504088896340736f;
    const float CLIP = 50.0f  * 1.44269504088896340736f;

    for (int a = 0; a < 2; ++a) {
        const int i = i0 + a;
        __syncthreads();                   // protect reused buffers across a
        if (t == 0) npos_cnt = 0;
        if (t < 4) wave_part[t] = 0.f;
        __syncthreads();
        const int li = labels[i];
        for (int k = t; k < NN; k += 256) {
            srow[k] = S[i * NN + k];
            bool p  = (labels[k] == li) && (k != i);
            posf[k] = p ? 1.f : 0.f;
            if (p) { int idx = atomicAdd(&npos_cnt, 1); poslist[idx] = k; }
        }
        __syncthreads();

        const int cnt = npos_cnt;          // positives excluding self
        if (cnt == 0) {                    // n_pos == 1 -> per_anchor = 0
            if (t == 0) pa_out[a] = 0.f;
            continue;
        }

        float acc = 0.f;                   // lane-0 accumulation per wave
        for (int idx = wave; idx <= cnt; idx += 4) {   // idx==cnt -> j==i (eye)
            const int   j   = (idx == cnt) ? i : poslist[idx];
            const float sij = srow[j];
            float sum_all = 0.f, sum_pos = 0.f;
#pragma unroll
            for (int kk = 0; kk < 8; kk++) {
                const int k = lane + (kk << 6);
                float y = (sij - srow[k]) * C1;
                y = fminf(fmaxf(y, -CLIP), CLIP);
                float tt = 1.0f / (1.0f + exp2f(y));
                if (k == j) tt = 0.f;      // (1-eye)[j,k] factor
                sum_all += tt;
                sum_pos += tt * posf[k];   // posf[i]==0 excludes k==i
            }
#pragma unroll
            for (int off = 32; off; off >>= 1) {
                sum_all += __shfl_down(sum_all, off);
                sum_pos += __shfl_down(sum_pos, off);
            }
            if (lane == 0) {
                const float den = 1.0f + sum_all;
                acc += ((j == i) ? 1.0f : (1.0f + sum_pos)) / den;
            }
        }
        if (lane == 0) wave_part[wave] = acc;
        __syncthreads();
        if (t == 0) {
            pa_out[a] = (wave_part[0] + wave_part[1] + wave_part[2] + wave_part[3])
                      / (float)(cnt + 1);
        }
    }
    __syncthreads();

    // ---- publish this block's two per_anchor values + flag (relaxed atomics)
    if (t == 0) {
        __hip_atomic_store(&pa_bits[i0],     __float_as_uint(pa_out[0]),
                           __ATOMIC_RELAXED, __HIP_MEMORY_SCOPE_AGENT);
        __hip_atomic_store(&pa_bits[i0 + 1], __float_as_uint(pa_out[1]),
                           __ATOMIC_RELAXED, __HIP_MEMORY_SCOPE_AGENT);
        // order data-atomics before flag-atomic without any cache writeback:
        asm volatile("s_waitcnt vmcnt(0)" ::: "memory");
        __hip_atomic_store(&flags[b], FMAGIC,
                           __ATOMIC_RELAXED, __HIP_MEMORY_SCOPE_AGENT);
    }

    if (b != 0) return;                    // finisher is block 0

    // ---- block 0: wait for all flags (relaxed polls -> no L2 inv storm)
    while (__hip_atomic_load(&flags[t], __ATOMIC_RELAXED,
                             __HIP_MEMORY_SCOPE_AGENT) != FMAGIC)
        __builtin_amdgcn_s_sleep(8);
    // reset for replay-robustness (0 != FMAGIC)
    __hip_atomic_store(&flags[t], 0u, __ATOMIC_RELAXED,
                       __HIP_MEMORY_SCOPE_AGENT);
    __syncthreads();

    // ---- final reduce (bitwise-identical round-0 tree)
    {
        float v0 = __uint_as_float(__hip_atomic_load(&pa_bits[t], __ATOMIC_RELAXED,
                                                     __HIP_MEMORY_SCOPE_AGENT));
        float v1 = __uint_as_float(__hip_atomic_load(&pa_bits[t + 256], __ATOMIC_RELAXED,
                                                     __HIP_MEMORY_SCOPE_AGENT));
        sh[t] = v0 + v1;
    }
    __syncthreads();
    for (int s = 128; s; s >>= 1) {
        if (t < s) sh[t] += sh[t + s];
        __syncthreads();
    }
    if (t == 0) out[0] = 1.0f - sh[0] / (float)NN;
}

extern "C" void kernel_launch(void* const* d_in, const int* in_sizes, int n_in,
                              void* d_out, int out_size, void* d_ws, size_t ws_size,
                              hipStream_t stream) {
    const float* preds  = (const float*)d_in[0];
    const int*   labels = (const int*)d_in[1];
    float* out = (float*)d_out;

    float*    S       = (float*)d_ws;                      // 512*512 floats = 1 MB
    unsigned* pa_bits = (unsigned*)((float*)d_ws + NN * NN);   // 512 u32
    unsigned* flags   = pa_bits + NN;                          // 256 u32

    dim3 ggrid(NN / 32, NN / 32);
    sap_gemm<<<ggrid, 256, 0, stream>>>(preds, S);
    sap_rows2<<<NN / 2, 256, 0, stream>>>(S, labels, pa_bits, flags, out);
}

// Round 8
// 73.071 us; speedup vs baseline: 1.1261x; 1.1261x over previous
//
#include <hip/hip_runtime.h>

#define NN 512
#define NB 256                 // 256 blocks x 2 anchors each
#define FMAGIC 0x5AD0F1A6u

// ---------------- single kernel: per-block srow dots + rows + atomic tail ----
// 256 blocks x 512 threads, 2 anchors per block (i = 2b, 2b+1).
// r4/r5/r6 lesson: the dot phase is an L2 SAME-LINE HOTSPOT -- all blocks
// walked the same 1 MB of P in the same order simultaneously, serializing on
// L2 slice ports (11.6 TB/s effective vs 34.5 µbench). Fix: rotate each
// block's row-visit ORDER by (b*37)&511. Per-(i,k) dot math and lane order
// are unchanged -> srow bitwise identical -> absmax 0.
// Grid-wide data flow remains only the final 512-float sum via RELAXED
// agent-scope atomics (no L2 writeback/invalidate storm -- round-3 lesson).
__global__ __launch_bounds__(512) void sap_fused(const float* __restrict__ P,
                                                 const int* __restrict__ labels,
                                                 unsigned* __restrict__ pa_bits,
                                                 unsigned* __restrict__ flags,
                                                 float* __restrict__ out) {
    __shared__ float srow[2][NN];
    __shared__ int   labels_sh[NN];
    __shared__ float posf[NN];
    __shared__ int   poslist[NN];
    __shared__ int   npos_cnt;
    __shared__ float wave_part[8];
    __shared__ float pa_out[2];
    __shared__ float sh[256];

    const int t    = threadIdx.x;          // 0..511
    const int lane = t & 63;
    const int wave = t >> 6;               // 0..7
    const int g    = lane & 15;            // lane within 16-group
    const int grp  = lane >> 4;            // 0..3: row-group within wave
    const int b    = blockIdx.x;
    const int i0   = b * 2;
    const int roff = (b * 37) & (NN - 1);  // per-block row rotation (hotspot fix)

    if (t < 128) ((int4*)labels_sh)[t] = ((const int4*)labels)[t];

    // ---- anchor rows into registers: lane's slots are float4 indices {g+16c}
    float4 a0[8], a1[8];
    {
        const float4* A0 = (const float4*)&P[i0 * NN];
        const float4* A1 = (const float4*)&P[(i0 + 1) * NN];
#pragma unroll
        for (int c = 0; c < 8; ++c) {
            a0[c] = A0[g + 16 * c];
            a1[c] = A1[g + 16 * c];
        }
    }

    // ---- dot phase: rotated row order; 4 rows in flight per batch per wave
#pragma unroll 4
    for (int bb_ = 0; bb_ < 16; ++bb_) {
        const int k = (wave * 64 + bb_ * 4 + grp + roff) & (NN - 1);
        const float4* B = (const float4*)&P[k * NN];
        float s0 = 0.f, s1 = 0.f;
#pragma unroll
        for (int c = 0; c < 8; ++c) {
            const float4 bb = B[g + 16 * c];
            s0 += a0[c].x * bb.x; s0 += a0[c].y * bb.y;
            s0 += a0[c].z * bb.z; s0 += a0[c].w * bb.w;
            s1 += a1[c].x * bb.x; s1 += a1[c].y * bb.y;
            s1 += a1[c].z * bb.z; s1 += a1[c].w * bb.w;
        }
#pragma unroll
        for (int off = 1; off < 16; off <<= 1) {   // stays within the 16-group
            s0 += __shfl_xor(s0, off);
            s1 += __shfl_xor(s1, off);
        }
        if (g == 0) { srow[0][k] = s0; srow[1][k] = s1; }
    }

    // ---- rows phase (verbatim round-4)
    const float C1   = 100.0f * 1.44269504088896340736f;
    const float CLIP = 50.0f  * 1.44269504088896340736f;

    for (int a = 0; a < 2; ++a) {
        const int i = i0 + a;
        __syncthreads();                   // srow ready / protect reused buffers
        if (t == 0) npos_cnt = 0;
        if (t < 8) wave_part[t] = 0.f;
        __syncthreads();
        const int li = labels_sh[i];
        {
            bool p  = (labels_sh[t] == li) && (t != i);
            posf[t] = p ? 1.f : 0.f;
            if (p) { int idx = atomicAdd(&npos_cnt, 1); poslist[idx] = t; }
        }
        __syncthreads();

        const int cnt = npos_cnt;          // positives excluding self
        if (cnt == 0) {                    // n_pos == 1 -> per_anchor = 0
            if (t == 0) pa_out[a] = 0.f;
            continue;
        }

        const float* sr = srow[a];
        float acc = 0.f;                   // lane-0 accumulation per wave
        for (int idx = wave; idx <= cnt; idx += 8) {   // idx==cnt -> j==i (eye)
            const int   j   = (idx == cnt) ? i : poslist[idx];
            const float sij = sr[j];
            float sum_all = 0.f, sum_pos = 0.f;
#pragma unroll
            for (int kk = 0; kk < 8; kk++) {
                const int k = lane + (kk << 6);
                float y = (sij - sr[k]) * C1;
                y = fminf(fmaxf(y, -CLIP), CLIP);
                float tt = 1.0f / (1.0f + exp2f(y));
                if (k == j) tt = 0.f;      // (1-eye)[j,k] factor
                sum_all += tt;
                sum_pos += tt * posf[k];   // posf[i]==0 excludes k==i
            }
#pragma unroll
            for (int off = 32; off; off >>= 1) {
                sum_all += __shfl_down(sum_all, off);
                sum_pos += __shfl_down(sum_pos, off);
            }
            if (lane == 0) {
                const float den = 1.0f + sum_all;
                acc += ((j == i) ? 1.0f : (1.0f + sum_pos)) / den;
            }
        }
        if (lane == 0) wave_part[wave] = acc;
        __syncthreads();
        if (t == 0) {
            float tot = 0.f;
#pragma unroll
            for (int w = 0; w < 8; ++w) tot += wave_part[w];
            pa_out[a] = tot / (float)(cnt + 1);
        }
    }
    __syncthreads();

    // ---- publish this block's two per_anchor values + flag (relaxed atomics)
    if (t == 0) {
        __hip_atomic_store(&pa_bits[i0],     __float_as_uint(pa_out[0]),
                           __ATOMIC_RELAXED, __HIP_MEMORY_SCOPE_AGENT);
        __hip_atomic_store(&pa_bits[i0 + 1], __float_as_uint(pa_out[1]),
                           __ATOMIC_RELAXED, __HIP_MEMORY_SCOPE_AGENT);
        // order data-atomics before flag-atomic without any cache writeback:
        asm volatile("s_waitcnt vmcnt(0)" ::: "memory");
        __hip_atomic_store(&flags[b], FMAGIC,
                           __ATOMIC_RELAXED, __HIP_MEMORY_SCOPE_AGENT);
    }

    if (b != 0) return;                    // finisher is block 0

    // ---- block 0: wait for all flags (relaxed polls -> no L2 inv storm)
    if (t < NB) {
        while (__hip_atomic_load(&flags[t], __ATOMIC_RELAXED,
                                 __HIP_MEMORY_SCOPE_AGENT) != FMAGIC)
            __builtin_amdgcn_s_sleep(8);
        // reset for replay-robustness (0 != FMAGIC)
        __hip_atomic_store(&flags[t], 0u, __ATOMIC_RELAXED,
                           __HIP_MEMORY_SCOPE_AGENT);
    }
    __syncthreads();

    // ---- final reduce (bitwise-identical round-0 tree)
    if (t < 256) {
        float v0 = __uint_as_float(__hip_atomic_load(&pa_bits[t], __ATOMIC_RELAXED,
                                                     __HIP_MEMORY_SCOPE_AGENT));
        float v1 = __uint_as_float(__hip_atomic_load(&pa_bits[t + 256], __ATOMIC_RELAXED,
                                                     __HIP_MEMORY_SCOPE_AGENT));
        sh[t] = v0 + v1;
    }
    __syncthreads();
    for (int s = 128; s; s >>= 1) {
        if (t < s) sh[t] += sh[t + s];
        __syncthreads();
    }
    if (t == 0) out[0] = 1.0f - sh[0] / (float)NN;
}

extern "C" void kernel_launch(void* const* d_in, const int* in_sizes, int n_in,
                              void* d_out, int out_size, void* d_ws, size_t ws_size,
                              hipStream_t stream) {
    const float* preds  = (const float*)d_in[0];
    const int*   labels = (const int*)d_in[1];
    float* out = (float*)d_out;

    unsigned* pa_bits = (unsigned*)d_ws;           // 512 u32 (float bits)
    unsigned* flags   = pa_bits + NN;              // 256 u32

    sap_fused<<<NB, 512, 0, stream>>>(preds, labels, pa_bits, flags, out);
}